// Round 1
// baseline (2360.363 us; speedup 1.0000x reference)
//
#include <hip/hip_runtime.h>

#define NUM_CLASSES 19
#define FEAT_CH 512
#define ACC_SLOTS (NUM_CLASSES * FEAT_CH)  // 9728

constexpr int BLOCK = 512;
constexpr int NBLK  = 1024;  // 4 blocks/CU * 256 CUs; 38KB LDS -> exactly 4/CU, 32 waves/CU

// Stage 1: block-local LDS accumulation, then global atomic flush.
// LDS layout swizzle: channel (4*cg + j) stored at [class*512 + j*128 + cg]
// so ds_add_f32 addresses are stride-1 across lanes (2 lanes/bank = free).
__global__ __launch_bounds__(BLOCK, 8)
void bars_accum_kernel(const float* __restrict__ feat,
                       const int* __restrict__ labels,
                       const int* __restrict__ ignore_p,
                       float* __restrict__ gsum,   // [ACC_SLOTS] (c*512 + ch, natural layout)
                       float* __restrict__ gcnt,   // [NUM_CLASSES]
                       int n) {
    __shared__ float ssum[ACC_SLOTS];
    __shared__ float scnt[NUM_CLASSES];

    const int tid = threadIdx.x;
    for (int s = tid; s < ACC_SLOTS; s += BLOCK) ssum[s] = 0.f;
    if (tid < NUM_CLASSES) scnt[tid] = 0.f;
    __syncthreads();

    const int ign = ignore_p[0];

    // contiguous pixel chunk per block (L2/TLB friendly streaming)
    const int per_blk = (n + (int)gridDim.x - 1) / (int)gridDim.x;
    const int p_begin = (int)blockIdx.x * per_blk;
    const int p_end   = min(n, p_begin + per_blk);

    const int sub = tid >> 7;   // which of 4 pixels this iteration
    const int cg  = tid & 127;  // float4 channel-group
    const float4* __restrict__ feat4 = (const float4*)feat;

    for (int p0 = p_begin; p0 < p_end; p0 += 4) {
        const int p = p0 + sub;
        if (p < p_end) {
            const int lab = labels[p];  // wave-uniform (all lanes same pixel)
            if (lab != ign) {           // wave-uniform branch; skips 2KB contiguous read
                const float4 v = feat4[(size_t)p * (FEAT_CH / 4) + cg];
                float* dst = &ssum[lab * FEAT_CH];
                atomicAdd(&dst[0 * 128 + cg], v.x);  // ds_add_f32, stride-1 banks
                atomicAdd(&dst[1 * 128 + cg], v.y);
                atomicAdd(&dst[2 * 128 + cg], v.z);
                atomicAdd(&dst[3 * 128 + cg], v.w);
                if (cg == 0) atomicAdd(&scnt[lab], 1.0f);
            }
        }
    }
    __syncthreads();

    // Flush LDS partials -> global accumulators (un-swizzle to natural c*512+ch).
    for (int g = tid; g < ACC_SLOTS; g += BLOCK) {
        const int c   = g >> 9;
        const int ch  = g & 511;
        const int j   = ch & 3;
        const int cgf = ch >> 2;
        const float v = ssum[c * FEAT_CH + j * 128 + cgf];
        if (v != 0.f) atomicAdd(&gsum[g], v);  // gsum pre-zeroed; skip empty classes
    }
    if (tid < NUM_CLASSES) {
        const float c = scnt[tid];
        if (c != 0.f) atomicAdd(&gcnt[tid], c);
    }
}

// Stage 2: finalize mean / sum_weight / class_dist into d_out.
__global__ void bars_finalize_kernel(const float* __restrict__ gsum,
                                     const float* __restrict__ gcnt,
                                     float* __restrict__ out) {
    const int i = blockIdx.x * blockDim.x + threadIdx.x;
    if (i < ACC_SLOTS) {
        const int c = i >> 9;
        const float cnt = gcnt[c];
        const float amt = (cnt == 0.f) ? 1.f : cnt;
        out[i] = gsum[i] / amt;                 // mean
        out[ACC_SLOTS + i] = cnt;               // sum_weight (broadcast counts)
    }
    if (i < NUM_CLASSES) {
        out[2 * ACC_SLOTS + i] = gcnt[i];       // class_dist
    }
}

extern "C" void kernel_launch(void* const* d_in, const int* in_sizes, int n_in,
                              void* d_out, int out_size, void* d_ws, size_t ws_size,
                              hipStream_t stream) {
    const float* feat   = (const float*)d_in[0];
    const int*   labels = (const int*)d_in[1];
    const int*   ign    = (const int*)d_in[2];
    float*       out    = (float*)d_out;

    const int n = in_sizes[1];  // number of pixels (labels element count)

    float* gsum = (float*)d_ws;
    float* gcnt = gsum + ACC_SLOTS;

    hipMemsetAsync(d_ws, 0, (ACC_SLOTS + NUM_CLASSES) * sizeof(float), stream);
    bars_accum_kernel<<<NBLK, BLOCK, 0, stream>>>(feat, labels, ign, gsum, gcnt, n);
    bars_finalize_kernel<<<(ACC_SLOTS + 255) / 256, 256, 0, stream>>>(gsum, gcnt, out);
}